// Round 1
// baseline (14837.889 us; speedup 1.0000x reference)
//
#include <hip/hip_runtime.h>
#include <hip/hip_bf16.h>

// ---------- types ----------
typedef short s8v __attribute__((ext_vector_type(8)));   // 8 bf16 in 4 VGPRs
typedef float f4v __attribute__((ext_vector_type(4)));

__device__ inline unsigned short f2bf(float f) {
  union { float f; unsigned int u; } v; v.f = f;
  unsigned int r = (v.u + 0x7fffu + ((v.u >> 16) & 1u)) >> 16;  // RNE
  return (unsigned short)r;
}
__device__ inline float bf2f(unsigned short h) {
  union { unsigned int u; float f; } v; v.u = ((unsigned int)h) << 16;
  return v.f;
}

// ---------------------------------------------------------------------------
// Phase 1: xV = x @ Vw^T + Vb.  M=131072, N=512, K=512, A/B fp32 converted to
// bf16 during LDS staging. 128x128 tile, 4 waves (2x2), 4x4 MFMA tiles/wave.
// ---------------------------------------------------------------------------
__global__ __launch_bounds__(256) void gemm_xv(const float* __restrict__ x,
                                               const float* __restrict__ Vw,
                                               const float* __restrict__ Vb,
                                               float* __restrict__ out) {
  // pitch 40 bf16 (pad 8) -> row start 80B: 16B-aligned, banks spread (20 words)
  __shared__ unsigned short As[128][40];
  __shared__ unsigned short Bs[128][40];
  const int tid  = threadIdx.x;
  const int lane = tid & 63;
  const int wv   = tid >> 6;
  const int wm   = wv & 1, wn = wv >> 1;
  const int q    = lane >> 4, mr = lane & 15;
  const int rowBase = blockIdx.y * 128;
  const int colBase = blockIdx.x * 128;

  f4v acc[4][4] = {};

  for (int k0 = 0; k0 < 512; k0 += 32) {
#pragma unroll
    for (int r = 0; r < 4; ++r) {
      int idx = tid + (r << 8);
      int arow = idx >> 3, ac = idx & 7;          // 8 float4 per row of 32
      const float4 av = *(const float4*)(x + (size_t)(rowBase + arow) * 512 + k0 + (ac << 2));
      ushort4 ap;
      ap.x = f2bf(av.x); ap.y = f2bf(av.y); ap.z = f2bf(av.z); ap.w = f2bf(av.w);
      *(ushort4*)&As[arow][ac << 2] = ap;
      const float4 bv = *(const float4*)(Vw + (size_t)(colBase + arow) * 512 + k0 + (ac << 2));
      ushort4 bp;
      bp.x = f2bf(bv.x); bp.y = f2bf(bv.y); bp.z = f2bf(bv.z); bp.w = f2bf(bv.w);
      *(ushort4*)&Bs[arow][ac << 2] = bp;
    }
    __syncthreads();
    s8v af[4], bf_[4];
#pragma unroll
    for (int mt = 0; mt < 4; ++mt)
      af[mt] = *(const s8v*)&As[wm * 64 + mt * 16 + mr][q * 8];
#pragma unroll
    for (int nt = 0; nt < 4; ++nt)
      bf_[nt] = *(const s8v*)&Bs[wn * 64 + nt * 16 + mr][q * 8];
#pragma unroll
    for (int mt = 0; mt < 4; ++mt)
#pragma unroll
      for (int nt = 0; nt < 4; ++nt)
        acc[mt][nt] = __builtin_amdgcn_mfma_f32_16x16x32_bf16(af[mt], bf_[nt], acc[mt][nt], 0, 0, 0);
    __syncthreads();
  }

  // Epilogue. C/D: col = lane&15 (n), row = (lane>>4)*4 + reg (m).
#pragma unroll
  for (int nt = 0; nt < 4; ++nt) {
    int col = colBase + wn * 64 + nt * 16 + mr;
    float vb = Vb[col];
#pragma unroll
    for (int mt = 0; mt < 4; ++mt) {
      int row0 = rowBase + wm * 64 + mt * 16 + q * 4;
#pragma unroll
      for (int e = 0; e < 4; ++e)
        out[(size_t)(row0 + e) * 512 + col] = acc[mt][nt][e] + vb;
    }
  }
}

// ---------------------------------------------------------------------------
// Phase 2: persistent recurrence. 256 WGs = 16 batch-bands x 16 H-slices,
// one per CU. W-slice lives split-bf16 in registers for all 512 steps.
// 3-MFMA split product per tile for ~fp32 accuracy. Band-local flag sync.
// ---------------------------------------------------------------------------
__global__ __launch_bounds__(256) void rnn_steps(const float* __restrict__ Ww,
                                                 const float* __restrict__ Wb,
                                                 float* __restrict__ out,
                                                 unsigned short* __restrict__ hb1,
                                                 unsigned short* __restrict__ hb2,
                                                 int* __restrict__ arrive) {
  const int band  = blockIdx.x >> 4;   // 16 bands of 16 batch rows
  const int slice = blockIdx.x & 15;   // 16 slices of 32 H cols
  const int tid  = threadIdx.x;
  const int lane = tid & 63;
  const int wv   = tid >> 6;           // wave owns K-chunk [128*wv, 128*wv+128)
  const int q    = lane >> 4, mr = lane & 15;

  __shared__ float plds[4][16][34];    // [wave][m][n] partial C, padded

  // ---- preload W fragments (split bf16) into registers: 64 VGPRs ----
  s8v w1[2][4], w2[2][4];
#pragma unroll
  for (int nt = 0; nt < 2; ++nt) {
    int n = slice * 32 + nt * 16 + mr;          // Ww row (output col)
#pragma unroll
    for (int s = 0; s < 4; ++s) {
      int kb = wv * 128 + s * 32 + q * 8;
      const float* wp = Ww + (size_t)n * 512 + kb;
      s8v v1, v2;
#pragma unroll
      for (int e = 0; e < 8; ++e) {
        float f = wp[e];
        unsigned short a = f2bf(f);
        unsigned short b = f2bf(f - bf2f(a));
        v1[e] = (short)a; v2[e] = (short)b;
      }
      w1[nt][s] = v1; w2[nt][s] = v2;
    }
  }

  float* outLast = out + (size_t)512 * 256 * 512;
  const int arow = band * 16 + mr;              // this lane's h row for A-frags

  for (int t = 0; t < 512; ++t) {
    f4v acc[2] = {};
    if (t > 0) {
      if (tid == 0) {
        const int target = t * 16;
        long long guard = 0;
        while (__hip_atomic_load(&arrive[band * 32], __ATOMIC_RELAXED,
                                 __HIP_MEMORY_SCOPE_AGENT) < target) {
          __builtin_amdgcn_s_sleep(2);
          if (++guard > (1LL << 28)) break;     // safety: never hang the bench
        }
      }
      __syncthreads();
      __threadfence();                          // acquire: invalidate stale L1/L2
      const size_t pofs = (size_t)((t - 1) & 1) * 131072;
      const unsigned short* p1 = hb1 + pofs + (size_t)arow * 512;
      const unsigned short* p2 = hb2 + pofs + (size_t)arow * 512;
#pragma unroll
      for (int s = 0; s < 4; ++s) {
        int kb = wv * 128 + s * 32 + q * 8;
        s8v a1 = *(const s8v*)(p1 + kb);
        s8v a2 = *(const s8v*)(p2 + kb);
#pragma unroll
        for (int nt = 0; nt < 2; ++nt) {
          acc[nt] = __builtin_amdgcn_mfma_f32_16x16x32_bf16(a1, w1[nt][s], acc[nt], 0, 0, 0);
          acc[nt] = __builtin_amdgcn_mfma_f32_16x16x32_bf16(a1, w2[nt][s], acc[nt], 0, 0, 0);
          acc[nt] = __builtin_amdgcn_mfma_f32_16x16x32_bf16(a2, w1[nt][s], acc[nt], 0, 0, 0);
        }
      }
    }
    // cross-wave K-reduction via LDS
#pragma unroll
    for (int nt = 0; nt < 2; ++nt)
#pragma unroll
      for (int e = 0; e < 4; ++e)
        plds[wv][q * 4 + e][nt * 16 + mr] = acc[nt][e];
    __syncthreads();

    const size_t par = (size_t)(t & 1) * 131072;
#pragma unroll
    for (int r = 0; r < 2; ++r) {
      int idx = tid + (r << 8);
      int m = idx >> 5, n = idx & 31;
      float z = plds[0][m][n] + plds[1][m][n] + plds[2][m][n] + plds[3][m][n];
      int row = band * 16 + m, col = slice * 32 + n;
      size_t oidx = (size_t)t * 131072 + (size_t)row * 512 + col;
      z += out[oidx] + Wb[col];                 // xv was staged in-place in d_out
      // tanh via exp2-free libm is fine (2 calls/thread/step)
      float v = tanhf(z);
      out[oidx] = v;
      if (t == 511) outLast[(size_t)row * 512 + col] = v;
      unsigned short h1 = f2bf(v);
      unsigned short h2 = f2bf(v - bf2f(h1));
      hb1[par + (size_t)row * 512 + col] = h1;
      hb2[par + (size_t)row * 512 + col] = h2;
    }
    __syncthreads();                            // drains vmcnt: stores are in L2
    if (tid == 0) {
      __threadfence();                          // release: push L2 past XCD
      atomicAdd(&arrive[band * 32], 1);         // device-scope by default
    }
  }
}

// ---------------------------------------------------------------------------
extern "C" void kernel_launch(void* const* d_in, const int* in_sizes, int n_in,
                              void* d_out, int out_size, void* d_ws, size_t ws_size,
                              hipStream_t stream) {
  const float* x  = (const float*)d_in[0];
  const float* Vw = (const float*)d_in[1];
  const float* Vb = (const float*)d_in[2];
  const float* Ww = (const float*)d_in[3];
  const float* Wb = (const float*)d_in[4];
  float* out = (float*)d_out;

  // ws layout: [0,4096) flag counters (128B-strided), then h ping-pong bf16 splits
  int* arrive = (int*)d_ws;
  unsigned short* hb1 = (unsigned short*)((char*)d_ws + 4096);
  unsigned short* hb2 = (unsigned short*)((char*)d_ws + 4096 + 2 * 131072 * sizeof(unsigned short));

  hipMemsetAsync(d_ws, 0, 4096, stream);        // zero arrive counters (ws is poisoned)
  gemm_xv<<<dim3(4, 1024), 256, 0, stream>>>(x, Vw, Vb, out);
  rnn_steps<<<dim3(256), 256, 0, stream>>>(Ww, Wb, out, hb1, hb2, arrive);
}